// Round 11
// baseline (633.915 us; speedup 1.0000x reference)
//
#include <hip/hip_runtime.h>
#include <hip/hip_fp16.h>

#define TSTEPS 276
#define NBATCH 32768
#define KDIM   4416   // 276*16
#define NPAD   320    // Wfc rows padded to 4*80
#define NOUT   276
#define NTILE  138    // KDIM / 32 = TSTEPS / 2
#define BTILE_ELE (320 * 32)     // elements per k-tile of W2t (10240)
#define BROWS  16     // batch rows per block (256-thread blocks)

typedef _Float16 half8 __attribute__((ext_vector_type(8)));
typedef float    f32x4 __attribute__((ext_vector_type(4)));
typedef float    f32x2 __attribute__((ext_vector_type(2)));

__device__ __forceinline__ float fast_sigmoid(float x) {
    float e = __builtin_amdgcn_exp2f(-1.4426950408889634f * x);
    return __builtin_amdgcn_rcpf(1.0f + e);
}
__device__ __forceinline__ float fast_tanh(float x) {
    float e = __builtin_amdgcn_exp2f(2.885390081777927f * x);
    return 1.0f - 2.0f * __builtin_amdgcn_rcpf(1.0f + e);
}

// packed 2xf32 FMA (VOP3P, bit-exact IEEE fma on both halves)
__device__ __forceinline__ f32x2 pk_fma(f32x2 a, f32x2 b, f32x2 c) {
    f32x2 d;
    asm("v_pk_fma_f32 %0, %1, %2, %3" : "=v"(d) : "v"(a), "v"(b), "v"(c));
    return d;
}

// broadcast h from lane (lane&0x18)|j within each 8-lane group (BitMode swizzle)
#define HSWZ1(hb, j) __int_as_float(__builtin_amdgcn_ds_swizzle(hb, ((j) << 5) | 0x18))

// ---------------- Kernel 1: Wfc fp32 -> fp16, K-permutation + B-TILING ------
// (unchanged, validated) W2t[k/32][320][32] fp16 = MFMA-fragment-native B.
__global__ __launch_bounds__(256) void conv_kernel(const float* __restrict__ Wfc,
                                                   _Float16* __restrict__ W2t)
{
    int i = blockIdx.x * 256 + threadIdx.x;        // destination index
    if (i < NPAD * KDIM) {
        int nk = i / BTILE_ELE;                    // k-tile index
        int r  = i - nk * BTILE_ELE;
        int n  = r >> 5;                           // 0..319 output row
        int kc = r & 31;
        int p  = nk * 32 + kc;                     // logical k
        _Float16 v = (_Float16)0.0f;
        if (n < NOUT) {
            int s = p >> 4, rr = p & 15;
            int src = (rr < 8) ? p : ((TSTEPS - 1 - s) * 16 + rr);
            v = (_Float16)Wfc[n * KDIM + src];
        }
        W2t[i] = v;
    }
}

// ---------------- Kernel 2: FUSED bidirectional LSTM + FC GEMM --------------
// R11: R8/R10 both stall at VALUBusy ~78% regardless of block size ->
// the ~22% idle is intra-wave serial structure, not barrier co-residency.
// Two changes:
// (a) v_pk_fma_f32 gate math packed across j-PAIRS (not gate-pairs): each
//     gate's partial is an (even-j, odd-j) f32x2; hv pairs are built from two
//     swizzle results (REG_SEQUENCE, no dup movs); the x-term uses the
//     naturally-paired (x0,x1): 40 scalar FMA -> 20 pk_fma + 4 adds. IEEE
//     bit-exact vs fmaf.
// (b) MFMA software-pipelined one tile back: at iter t, issue the 5 B-loads
//     (pbase + imm offsets) and ds_read for tile t-1 up front, LSTM step A
//     hides their latency, MFMA(t-1) runs mid-iteration, step B, barrier.
//     The post-barrier serial ds_read->MFMA block leaves the critical path.
//     Hazard audit: read(t-1) precedes barrier(t); the overwrite of that
//     buffer happens at iter t+1 after barrier(t).
__global__ __launch_bounds__(256, 4) void fused_kernel(
    const float* __restrict__ x,
    const float* __restrict__ Wih_f, const float* __restrict__ Whh_f,
    const float* __restrict__ bih_f, const float* __restrict__ bhh_f,
    const float* __restrict__ Wih_b, const float* __restrict__ Whh_b,
    const float* __restrict__ bih_b, const float* __restrict__ bhh_b,
    const _Float16* __restrict__ W2, const float* __restrict__ bfc,
    float* __restrict__ out)
{
    __shared__ _Float16 sl[2][BROWS][32];          // double-buffered H k-tile, 2KB

    const int tid = threadIdx.x;
    const int k   = tid & 7;                       // hidden unit 0..7
    const int dir = (tid >> 3) & 1;
    const int row = tid >> 4;                      // local batch row 0..15
    const int m0  = blockIdx.x * BROWS;

    const float* Wih = dir ? Wih_b : Wih_f;
    const float* Whh = dir ? Whh_b : Whh_f;
    const float* bih = dir ? bih_b : bih_f;
    const float* bhh = dir ? bhh_b : bhh_f;

    // packed weights: Wh[g][jp] = (Whh[g][2jp], Whh[g][2jp+1]);
    // Wx[g] = (Wih[g][0], Wih[g][1]); bx[g] = (bias[g], 0)
    f32x2 Wh[4][4], Wx[4], bx[4];
    #pragma unroll
    for (int g = 0; g < 4; ++g) {
        const int wr = g * 8 + k;                  // PyTorch gate order i,f,g,o
        #pragma unroll
        for (int jp = 0; jp < 4; ++jp)
            Wh[g][jp] = f32x2{Whh[wr * 8 + 2 * jp], Whh[wr * 8 + 2 * jp + 1]};
        Wx[g] = f32x2{Wih[wr * 2 + 0], Wih[wr * 2 + 1]};
        bx[g] = f32x2{bih[wr] + bhh[wr], 0.0f};
    }
    #pragma unroll
    for (int g = 0; g < 4; ++g) {                  // pin in ArchVGPRs
        #pragma unroll
        for (int jp = 0; jp < 4; ++jp) asm("" : "+v"(Wh[g][jp]));
        asm("" : "+v"(Wx[g]));
        asm("" : "+v"(bx[g]));
    }

    const float2* xp = (const float2*)(x + (size_t)(m0 + row) * (TSTEPS * 2))
                       + (dir ? (TSTEPS - 1) : 0);
    const int xs  = dir ? -1 : 1;                  // float2 step per LSTM step
    const int xs2 = 2 * xs, xs3 = 3 * xs;

    // MFMA wave roles: 4 waves = 1(M) x 4(N); wave tile 16 rows x 80 cols
    const int lane = tid & 63;
    const int wn   = tid >> 6;                     // 0..3
    const int l15  = lane & 15;
    const int l4   = lane >> 4;
    const int arow = l15;                          // A-frag source row in slice
    const int aoff = (l4 ^ (arow & 3)) << 3;       // swizzled element offset

    // B fragment base: fragments ni=0..4 at imm offsets {-2048..+2048}
    const char* pbase = (const char*)W2 + (wn * 80 + l15) * 64 + l4 * 16 + 2048;

    f32x4 acc[5] = {};

    // swizzled chunk element offsets for the two steps of a pair
    const int c0 = ((0 | dir) ^ (row & 3)) << 3;   // s even: chunk = dir
    const int c1 = ((2 | dir) ^ (row & 3)) << 3;   // s odd : chunk = 2|dir

    float h = 0.0f, c = 0.0f;
    float2 xq0 = xp[0], xq1 = xp[xs];

    #pragma unroll 1
    for (int t = 0; t < NTILE; ++t) {
        // ---- issue tile t-1 operand loads early (latency hidden by step A) --
        half8 b0, b1, b2, b3, b4, a;
        if (t) {
            const char* pt = pbase + (size_t)(t - 1) * 20480;
            b0 = *(const half8*)(pt - 2048);
            b1 = *(const half8*)(pt - 1024);
            b2 = *(const half8*)(pt);
            b3 = *(const half8*)(pt + 1024);
            b4 = *(const half8*)(pt + 2048);
            a  = *(const half8*)(&sl[(t - 1) & 1][arow][aoff]);
        }
        // x prefetch for pair t+1 (guarded; uniform branch)
        float2 nx0 = xq0, nx1 = xq1;
        if (t + 1 < NTILE) { nx0 = xp[xs2]; nx1 = xp[xs3]; }

        _Float16* srow = &sl[t & 1][row][0];

        // ---- LSTM step s = 2t (x = xq0) ----
        {
            const int hb = __float_as_int(h);
            const f32x2 xqp = f32x2{xq0.x, xq0.y};
            f32x2 p0 = pk_fma(Wx[0], xqp, bx[0]);
            f32x2 p1 = pk_fma(Wx[1], xqp, bx[1]);
            f32x2 p2 = pk_fma(Wx[2], xqp, bx[2]);
            f32x2 p3 = pk_fma(Wx[3], xqp, bx[3]);
            const f32x2 hp01 = f32x2{HSWZ1(hb, 0), HSWZ1(hb, 1)};
            const f32x2 hp23 = f32x2{HSWZ1(hb, 2), HSWZ1(hb, 3)};
            const f32x2 hp45 = f32x2{HSWZ1(hb, 4), HSWZ1(hb, 5)};
            const f32x2 hp67 = f32x2{HSWZ1(hb, 6), HSWZ1(hb, 7)};
            p0 = pk_fma(Wh[0][0], hp01, p0); p1 = pk_fma(Wh[1][0], hp01, p1);
            p2 = pk_fma(Wh[2][0], hp01, p2); p3 = pk_fma(Wh[3][0], hp01, p3);
            p0 = pk_fma(Wh[0][1], hp23, p0); p1 = pk_fma(Wh[1][1], hp23, p1);
            p2 = pk_fma(Wh[2][1], hp23, p2); p3 = pk_fma(Wh[3][1], hp23, p3);
            p0 = pk_fma(Wh[0][2], hp45, p0); p1 = pk_fma(Wh[1][2], hp45, p1);
            p2 = pk_fma(Wh[2][2], hp45, p2); p3 = pk_fma(Wh[3][2], hp45, p3);
            p0 = pk_fma(Wh[0][3], hp67, p0); p1 = pk_fma(Wh[1][3], hp67, p1);
            p2 = pk_fma(Wh[2][3], hp67, p2); p3 = pk_fma(Wh[3][3], hp67, p3);
            const float ig = fast_sigmoid(p0.x + p0.y);
            const float fg = fast_sigmoid(p1.x + p1.y);
            const float gg = fast_tanh(p2.x + p2.y);
            const float og = fast_sigmoid(p3.x + p3.y);
            c = fmaf(fg, c, ig * gg);
            h = og * fast_tanh(c);
            srow[c0 + k] = (_Float16)h;
        }

        // ---- MFMA for tile t-1 (operands issued at iter top) ----
        if (t) {
            acc[0] = __builtin_amdgcn_mfma_f32_16x16x32_f16(a, b0, acc[0], 0, 0, 0);
            acc[1] = __builtin_amdgcn_mfma_f32_16x16x32_f16(a, b1, acc[1], 0, 0, 0);
            acc[2] = __builtin_amdgcn_mfma_f32_16x16x32_f16(a, b2, acc[2], 0, 0, 0);
            acc[3] = __builtin_amdgcn_mfma_f32_16x16x32_f16(a, b3, acc[3], 0, 0, 0);
            acc[4] = __builtin_amdgcn_mfma_f32_16x16x32_f16(a, b4, acc[4], 0, 0, 0);
        }

        // ---- LSTM step s = 2t+1 (x = xq1) ----
        {
            const int hb = __float_as_int(h);
            const f32x2 xqp = f32x2{xq1.x, xq1.y};
            f32x2 p0 = pk_fma(Wx[0], xqp, bx[0]);
            f32x2 p1 = pk_fma(Wx[1], xqp, bx[1]);
            f32x2 p2 = pk_fma(Wx[2], xqp, bx[2]);
            f32x2 p3 = pk_fma(Wx[3], xqp, bx[3]);
            const f32x2 hp01 = f32x2{HSWZ1(hb, 0), HSWZ1(hb, 1)};
            const f32x2 hp23 = f32x2{HSWZ1(hb, 2), HSWZ1(hb, 3)};
            const f32x2 hp45 = f32x2{HSWZ1(hb, 4), HSWZ1(hb, 5)};
            const f32x2 hp67 = f32x2{HSWZ1(hb, 6), HSWZ1(hb, 7)};
            p0 = pk_fma(Wh[0][0], hp01, p0); p1 = pk_fma(Wh[1][0], hp01, p1);
            p2 = pk_fma(Wh[2][0], hp01, p2); p3 = pk_fma(Wh[3][0], hp01, p3);
            p0 = pk_fma(Wh[0][1], hp23, p0); p1 = pk_fma(Wh[1][1], hp23, p1);
            p2 = pk_fma(Wh[2][1], hp23, p2); p3 = pk_fma(Wh[3][1], hp23, p3);
            p0 = pk_fma(Wh[0][2], hp45, p0); p1 = pk_fma(Wh[1][2], hp45, p1);
            p2 = pk_fma(Wh[2][2], hp45, p2); p3 = pk_fma(Wh[3][2], hp45, p3);
            p0 = pk_fma(Wh[0][3], hp67, p0); p1 = pk_fma(Wh[1][3], hp67, p1);
            p2 = pk_fma(Wh[2][3], hp67, p2); p3 = pk_fma(Wh[3][3], hp67, p3);
            const float ig = fast_sigmoid(p0.x + p0.y);
            const float fg = fast_sigmoid(p1.x + p1.y);
            const float gg = fast_tanh(p2.x + p2.y);
            const float og = fast_sigmoid(p3.x + p3.y);
            c = fmaf(fg, c, ig * gg);
            h = og * fast_tanh(c);
            srow[c1 + k] = (_Float16)h;
        }

        __syncthreads();                           // tile t complete in sl[t&1]

        xp += xs2;
        xq0 = nx0; xq1 = nx1;
    }

    // ---- epilogue: MFMA for the last tile (NTILE-1, in sl[1]) ----
    {
        const char* pt = pbase + (size_t)(NTILE - 1) * 20480;
        const half8 b0 = *(const half8*)(pt - 2048);
        const half8 b1 = *(const half8*)(pt - 1024);
        const half8 b2 = *(const half8*)(pt);
        const half8 b3 = *(const half8*)(pt + 1024);
        const half8 b4 = *(const half8*)(pt + 2048);
        const half8 a  = *(const half8*)(&sl[(NTILE - 1) & 1][arow][aoff]);
        acc[0] = __builtin_amdgcn_mfma_f32_16x16x32_f16(a, b0, acc[0], 0, 0, 0);
        acc[1] = __builtin_amdgcn_mfma_f32_16x16x32_f16(a, b1, acc[1], 0, 0, 0);
        acc[2] = __builtin_amdgcn_mfma_f32_16x16x32_f16(a, b2, acc[2], 0, 0, 0);
        acc[3] = __builtin_amdgcn_mfma_f32_16x16x32_f16(a, b3, acc[3], 0, 0, 0);
        acc[4] = __builtin_amdgcn_mfma_f32_16x16x32_f16(a, b4, acc[4], 0, 0, 0);
    }

    // epilogue: C layout col = l15 (N), row = l4*4 + g (M within 16-row tile)
    #pragma unroll
    for (int ni = 0; ni < 5; ++ni) {
        const int n = wn * 80 + ni * 16 + l15;
        if (n < NOUT) {
            const float bv = bfc[n];
            #pragma unroll
            for (int g = 0; g < 4; ++g)
                out[(size_t)(m0 + l4 * 4 + g) * NOUT + n] = acc[ni][g] + bv;
        }
    }
}

extern "C" void kernel_launch(void* const* d_in, const int* in_sizes, int n_in,
                              void* d_out, int out_size, void* d_ws, size_t ws_size,
                              hipStream_t stream) {
    const float* x     = (const float*)d_in[0];
    const float* Wih_f = (const float*)d_in[1];
    const float* Whh_f = (const float*)d_in[2];
    const float* bih_f = (const float*)d_in[3];
    const float* bhh_f = (const float*)d_in[4];
    const float* Wih_b = (const float*)d_in[5];
    const float* Whh_b = (const float*)d_in[6];
    const float* bih_b = (const float*)d_in[7];
    const float* bhh_b = (const float*)d_in[8];
    const float* Wfc   = (const float*)d_in[9];
    const float* bfc   = (const float*)d_in[10];
    float* out = (float*)d_out;

    _Float16* W2 = (_Float16*)d_ws;                // 2.76 MB, only workspace user

    conv_kernel<<<(NPAD * KDIM + 255) / 256, 256, 0, stream>>>(Wfc, W2);
    fused_kernel<<<NBATCH / BROWS, 256, 0, stream>>>(x, Wih_f, Whh_f, bih_f, bhh_f,
                                                     Wih_b, Whh_b, bih_b, bhh_b,
                                                     W2, bfc, out);
}